// Round 6
// baseline (213.880 us; speedup 1.0000x reference)
//
#include <hip/hip_runtime.h>
#include <hip/hip_bf16.h>

typedef __bf16 bf16x8 __attribute__((ext_vector_type(8)));
typedef float f32x4 __attribute__((ext_vector_type(4)));
typedef unsigned short u16x8 __attribute__((ext_vector_type(8)));
typedef unsigned short u16x4 __attribute__((ext_vector_type(4)));

#define HB 16
#define TT 2048
#define CCH 1024
#define DD 64

#define AS1 __attribute__((address_space(1)))
#define AS3 __attribute__((address_space(3)))
#define GL16(gp, lp) __builtin_amdgcn_global_load_lds((const AS1 void*)(gp), (AS3 void*)(lp), 16, 0, 0)

__device__ __forceinline__ unsigned short f2bf(float f) {
  union { __hip_bfloat16 h; unsigned short u; } cv;
  cv.h = __float2bfloat16(f);
  return cv.u;
}

// packed bf16 pair via single HW instr: D[15:0]=bf16(lo), D[31:16]=bf16(hi)
__device__ __forceinline__ unsigned pack2(float lo, float hi) {
  unsigned r;
  asm("v_cvt_pk_bf16_f32 %0, %1, %2" : "=v"(r) : "v"(lo), "v"(hi));
  return r;
}

__device__ __forceinline__ f32x4 mfma16(bf16x8 a, bf16x8 b, f32x4 c) {
  return __builtin_amdgcn_mfma_f32_16x16x32_bf16(a, b, c, 0, 0, 0);
}

// ---------------- conversion kernels ----------------

__global__ __launch_bounds__(256) void cvt_f32_bf16(const float* __restrict__ in,
                                                    unsigned short* __restrict__ out,
                                                    int n4) {
  int i = blockIdx.x * 256 + threadIdx.x;
  if (i >= n4) return;
  float4 v = reinterpret_cast<const float4*>(in)[i];
  u16x4 o;
  o.x = f2bf(v.x); o.y = f2bf(v.y); o.z = f2bf(v.z); o.w = f2bf(v.w);
  *reinterpret_cast<u16x4*>(out + (size_t)i * 4) = o;
}

// w: [1024 x N] fp32  ->  wt: [N x 1024] bf16 (transposed)
__global__ __launch_bounds__(256) void transpose_cvt(const float* __restrict__ w,
                                                     unsigned short* __restrict__ wt,
                                                     int N) {
  __shared__ unsigned short t[32][33];
  int nb = blockIdx.x * 32, kb = blockIdx.y * 32;
  int tx = threadIdx.x & 31, ty = threadIdx.x >> 5;  // ty 0..7
  #pragma unroll
  for (int r = 0; r < 32; r += 8)
    t[ty + r][tx] = f2bf(w[(size_t)(kb + ty + r) * N + nb + tx]);
  __syncthreads();
  #pragma unroll
  for (int r = 0; r < 32; r += 8)
    wt[(size_t)(nb + ty + r) * 1024 + kb + tx] = t[tx][ty + r];
}

// ---------------- GEMM (m97 structure): C = A @ Bt^T (+bias) ----------------

template <int EPI>
__global__ __launch_bounds__(256) void gemm_bf16(
    const unsigned short* __restrict__ A,
    const unsigned short* __restrict__ Bt,
    const float* __restrict__ bias,
    float* __restrict__ outf,
    unsigned short* __restrict__ qb,
    unsigned short* __restrict__ kb,
    unsigned short* __restrict__ vt) {
  __shared__ unsigned short As[8192];  // [128][64] linear
  __shared__ unsigned short Bs[8192];
  const int tid = threadIdx.x;
  const int lane = tid & 63;
  const int wid = tid >> 6;
  const int r16 = lane & 15, g = lane >> 4;
  const int wm = wid >> 1, wn = wid & 1;
  const int m0 = blockIdx.y * 128, n0 = blockIdx.x * 128;
  const int srow = tid >> 3;                 // 0..31 (+32 per instr)
  const int schx = (tid & 7) ^ (srow & 7);   // XOR-swizzled source chunk

  f32x4 acc[4][4];
  #pragma unroll
  for (int i = 0; i < 4; ++i)
    #pragma unroll
    for (int j = 0; j < 4; ++j) acc[i][j] = (f32x4){0.f, 0.f, 0.f, 0.f};

  const int rx = r16 & 7;

  for (int kt = 0; kt < 1024; kt += 64) {
    #pragma unroll
    for (int i = 0; i < 4; ++i) {
      const int row = i * 32 + srow;
      GL16(A + (size_t)(m0 + row) * 1024 + kt + schx * 8, As + i * 2048 + tid * 8);
    }
    #pragma unroll
    for (int i = 0; i < 4; ++i) {
      const int row = i * 32 + srow;
      GL16(Bt + (size_t)(n0 + row) * 1024 + kt + schx * 8, Bs + i * 2048 + tid * 8);
    }
    __syncthreads();
    #pragma unroll
    for (int h = 0; h < 2; ++h) {
      bf16x8 af[4], bfr[4];
      #pragma unroll
      for (int i = 0; i < 4; ++i)
        af[i] = *reinterpret_cast<const bf16x8*>(
            &As[(wm * 64 + i * 16 + r16) * 64 + ((g + 4 * h) ^ rx) * 8]);
      #pragma unroll
      for (int j = 0; j < 4; ++j)
        bfr[j] = *reinterpret_cast<const bf16x8*>(
            &Bs[(wn * 64 + j * 16 + r16) * 64 + ((g + 4 * h) ^ rx) * 8]);
      #pragma unroll
      for (int i = 0; i < 4; ++i)
        #pragma unroll
        for (int j = 0; j < 4; ++j)
          acc[i][j] = mfma16(af[i], bfr[j], acc[i][j]);
    }
    __syncthreads();
  }

  #pragma unroll
  for (int i = 0; i < 4; ++i) {
    #pragma unroll
    for (int j = 0; j < 4; ++j) {
      const int n = n0 + wn * 64 + j * 16 + r16;
      const int mbase = m0 + wm * 64 + i * 16 + g * 4;
      const float bi = bias[n];
      if (EPI == 1) {
        #pragma unroll
        for (int r = 0; r < 4; ++r)
          outf[(size_t)(mbase + r) * 1024 + n] = acc[i][j][r] + bi;
      } else {
        const int which = n >> 10;
        const int cc2 = n & 1023;
        const int h = cc2 >> 6, d = cc2 & 63;
        const int b = mbase >> 11, t = mbase & 2047;
        if (which == 2) {
          u16x4 o;
          #pragma unroll
          for (int r = 0; r < 4; ++r) o[r] = f2bf(acc[i][j][r] + bi);
          *reinterpret_cast<u16x4*>(
              &vt[(((size_t)b * HB + h) * DD + d) * TT + t]) = o;
        } else {
          unsigned short* dst = (which == 0) ? qb : kb;
          // q folded scale: 1/sqrt(64) * log2(e)  (exp2-domain softmax)
          const float sc = (which == 0) ? 0.18033688011112042f : 1.0f;
          #pragma unroll
          for (int r = 0; r < 4; ++r)
            dst[(((size_t)b * HB + h) * TT + (t + r)) * DD + d] =
                f2bf((acc[i][j][r] + bi) * sc);
        }
      }
    }
  }
}

// ---------------- flash attention ----------------
// grid (16, B*H), 256 thr = 4 waves, KVBLK=64, 16 q-rows/wave (64 q/block).
// Swapped QK^T (one q per lane). K/V TRIPLE-buffered (48 KB) via
// global_load_lds (XOR-swizzled source). T3/T4: counted vmcnt(4) + raw
// s_barrier ONLY (no vmcnt(0) drain in the loop); constant-rate staging with
// clamped (dummy) tail to keep the vmcnt invariant. Per-tile order:
//   vmcnt(4) ; s_barrier ; STAGE(t+2 -> buf[(t+2)%3]) ; compute(buf[t%3])
// Triangle pairing: part0 = q-group jb, part1 = q-group 31-jb -> 33 tiles/blk.

__global__ __launch_bounds__(256, 4) void attn_kernel(
    const unsigned short* __restrict__ qg_,
    const unsigned short* __restrict__ kg_,
    const unsigned short* __restrict__ vtg_,
    unsigned short* __restrict__ yb) {
  const int bh = blockIdx.y;
  const int jb = blockIdx.x;
  const int tid = threadIdx.x;
  const int wid = tid >> 6;
  const int lane = tid & 63;
  const int r16 = lane & 15, g = lane >> 4;
  const unsigned short* Q = qg_ + (size_t)bh * TT * DD;
  const unsigned short* K = kg_ + (size_t)bh * TT * DD;
  const unsigned short* Vt = vtg_ + (size_t)bh * DD * TT;
  const int b = bh >> 4, h = bh & 15;

  // per buffer: K [64][64] at 0..4096, V [64][64] at 4096..8192 (elems)
  __shared__ unsigned short smem[3][8192];

  const int krow0 = tid >> 3;                    // 0..31 (+32 per instr)
  const int chx = (tid & 7) ^ (krow0 & 7);       // XOR-swizzled source chunk
  const int rx = r16 & 7;

#define STAGE(bi_, kvb_) do {                                                   \
    unsigned short* sb_ = &smem[bi_][0];                                        \
    const unsigned short* gk_ = K + (size_t)(kvb_) * DD;                        \
    GL16(gk_ + (size_t)krow0 * DD + chx * 8,               sb_ + tid * 8);      \
    GL16(gk_ + (size_t)(32 + krow0) * DD + chx * 8,        sb_ + 2048 + tid * 8);\
    GL16(Vt + (size_t)krow0 * TT + (kvb_) + chx * 8,       sb_ + 4096 + tid * 8);\
    GL16(Vt + (size_t)(32 + krow0) * TT + (kvb_) + chx * 8, sb_ + 6144 + tid * 8);\
  } while (0)

  #pragma unroll
  for (int part = 0; part < 2; ++part) {
    const int qg0 = (part == 0) ? jb * 64 : (31 - jb) * 64;
    const int nt = (part == 0) ? (jb + 1) : (32 - jb);
    const int qw = qg0 + wid * 16;
    const int q = qw + r16;  // this lane's q row

    bf16x8 qf0 = *reinterpret_cast<const bf16x8*>(&Q[(size_t)q * DD + g * 8]);
    bf16x8 qf1 = *reinterpret_cast<const bf16x8*>(&Q[(size_t)q * DD + 32 + g * 8]);

    f32x4 yacc[4];
    #pragma unroll
    for (int db = 0; db < 4; ++db) yacc[db] = (f32x4){0.f, 0.f, 0.f, 0.f};
    float m = -1e30f, l = 0.f;

    // prologue: 2 tiles in flight (8 loads); tail-clamp keeps count invariant
    STAGE(0, 0);
    STAGE(1, (nt > 1 ? 1 : 0) * 64);
    int bi = 0;

    for (int t = 0; t < nt; ++t) {
      // T4: retire own tile-t loads (leave t+1's 4 flying); all-wave barrier
      // then makes buf[t%3] globally valid and frees buf[(t+2)%3].
      asm volatile("s_waitcnt vmcnt(4)" ::: "memory");
      __builtin_amdgcn_s_barrier();
      {
        int bs = bi + 2; if (bs >= 3) bs -= 3;
        const int tn = (t + 2 < nt) ? (t + 2) : (nt - 1);  // clamp -> dummy
        STAGE(bs, tn * 64);
      }

      const int kvb = t * 64;
      const unsigned short* sK = &smem[bi][0];
      const unsigned short* sV = &smem[bi][4096];

      // ---- S^T = K Q^T : lane holds S^T[kvb + c*16 + 4g + r][q] ----
      float s[4][4];
      __builtin_amdgcn_s_setprio(1);
      #pragma unroll
      for (int c = 0; c < 4; ++c) {
        bf16x8 kfa = *reinterpret_cast<const bf16x8*>(
            &sK[(c * 16 + r16) * 64 + (g ^ rx) * 8]);
        bf16x8 kfb = *reinterpret_cast<const bf16x8*>(
            &sK[(c * 16 + r16) * 64 + ((g + 4) ^ rx) * 8]);
        f32x4 z = (f32x4){0.f, 0.f, 0.f, 0.f};
        z = mfma16(kfa, qf0, z);
        z = mfma16(kfb, qf1, z);
        #pragma unroll
        for (int r = 0; r < 4; ++r) s[c][r] = z[r];
      }
      __builtin_amdgcn_s_setprio(0);

      // ---- mask (last tile only) + tree max ----
      if (t == nt - 1) {
        #pragma unroll
        for (int c = 0; c < 4; ++c)
          #pragma unroll
          for (int r = 0; r < 4; ++r)
            if (kvb + c * 16 + 4 * g + r > q) s[c][r] = -1e30f;
      }
      float mc[4];
      #pragma unroll
      for (int c = 0; c < 4; ++c)
        mc[c] = fmaxf(fmaxf(s[c][0], s[c][1]), fmaxf(s[c][2], s[c][3]));
      float mx = fmaxf(fmaxf(mc[0], mc[1]), fmaxf(mc[2], mc[3]));
      mx = fmaxf(mx, __shfl_xor(mx, 16));
      mx = fmaxf(mx, __shfl_xor(mx, 32));

      // ---- defer-max (T13, exp2 domain, THR=8) ----
      if (!__all(mx <= m + 8.f)) {
        const float mn = fmaxf(m, mx);
        const float al = exp2f(m - mn);
        m = mn;
        l *= al;
        #pragma unroll
        for (int db = 0; db < 4; ++db)
          #pragma unroll
          for (int r = 0; r < 4; ++r) yacc[db][r] *= al;
      }
      float sc4[4];
      #pragma unroll
      for (int c = 0; c < 4; ++c) {
        #pragma unroll
        for (int r = 0; r < 4; ++r) s[c][r] = exp2f(s[c][r] - m);
        sc4[c] = (s[c][0] + s[c][1]) + (s[c][2] + s[c][3]);
      }
      float rs = (sc4[0] + sc4[1]) + (sc4[2] + sc4[3]);
      rs += __shfl_xor(rs, 16);
      rs += __shfl_xor(rs, 32);
      l += rs;

      // ---- PV: per kk, build P^T B-frag by shuffles, A = V from LDS ----
      const int s0l = r16 + 16 * ((2 * g) & 3);
      const int s1l = r16 + 16 * ((2 * g + 1) & 3);
      #pragma unroll
      for (int kk = 0; kk < 2; ++kk) {
        const unsigned x0 = pack2(s[2 * kk][0], s[2 * kk][1]);
        const unsigned x1 = pack2(s[2 * kk][2], s[2 * kk][3]);
        const unsigned y0 = pack2(s[2 * kk + 1][0], s[2 * kk + 1][1]);
        const unsigned y1 = pack2(s[2 * kk + 1][2], s[2 * kk + 1][3]);
        unsigned a0 = __shfl((int)x0, s0l, 64);
        unsigned b0 = __shfl((int)y0, s0l, 64);
        unsigned a1 = __shfl((int)x1, s0l, 64);
        unsigned b1 = __shfl((int)y1, s0l, 64);
        unsigned a2 = __shfl((int)x0, s1l, 64);
        unsigned b2 = __shfl((int)y0, s1l, 64);
        unsigned a3 = __shfl((int)x1, s1l, 64);
        unsigned b3 = __shfl((int)y1, s1l, 64);
        union { unsigned w[4]; bf16x8 v; } pf;
        pf.w[0] = (g < 2) ? a0 : b0;
        pf.w[1] = (g < 2) ? a1 : b1;
        pf.w[2] = (g < 2) ? a2 : b2;
        pf.w[3] = (g < 2) ? a3 : b3;
        __builtin_amdgcn_s_setprio(1);
        #pragma unroll
        for (int db = 0; db < 4; ++db) {
          bf16x8 vf = *reinterpret_cast<const bf16x8*>(
              &sV[(db * 16 + r16) * 64 + ((kk * 4 + g) ^ rx) * 8]);
          yacc[db] = mfma16(vf, pf.v, yacc[db]);
        }
        __builtin_amdgcn_s_setprio(0);
      }

      bi = (bi == 2) ? 0 : bi + 1;
    }

    // ---- epilogue: y = yacc / l ----
    const float rl = 1.0f / l;
    #pragma unroll
    for (int db = 0; db < 4; ++db) {
      unsigned w0 = pack2(yacc[db][0] * rl, yacc[db][1] * rl);
      unsigned w1 = pack2(yacc[db][2] * rl, yacc[db][3] * rl);
      uint2 o = make_uint2(w0, w1);
      *reinterpret_cast<uint2*>(
          &yb[((size_t)b * TT + q) * CCH + h * DD + db * 16 + 4 * g]) = o;
    }
  }
#undef STAGE
}

// ---------------- launcher ----------------

extern "C" void kernel_launch(void* const* d_in, const int* in_sizes, int n_in,
                              void* d_out, int out_size, void* d_ws, size_t ws_size,
                              hipStream_t stream) {
  const float* x      = (const float*)d_in[0];
  const float* w_attn = (const float*)d_in[1];
  const float* b_attn = (const float*)d_in[2];
  const float* w_proj = (const float*)d_in[3];
  const float* b_proj = (const float*)d_in[4];
  float* out = (float*)d_out;
  char* ws = (char*)d_ws;

  unsigned short* xb  = (unsigned short*)(ws + 0);          // 16 MB
  unsigned short* wat = (unsigned short*)(ws + 16777216);   // 6 MB  [3072][1024]
  unsigned short* wpt = (unsigned short*)(ws + 23068672);   // 2 MB  [1024][1024]
  unsigned short* qb  = (unsigned short*)(ws + 25165824);   // 16 MB [B,H,T,D]
  unsigned short* kb  = (unsigned short*)(ws + 41943040);   // 16 MB [B,H,T,D]
  unsigned short* vt  = (unsigned short*)(ws + 58720256);   // 16 MB [B,H,D,T]
  unsigned short* yb  = (unsigned short*)(ws + 75497472);   // 16 MB [B,T,C]

  cvt_f32_bf16<<<(8192 * 1024 / 4 + 255) / 256, 256, 0, stream>>>(x, xb, 8192 * 1024 / 4);
  transpose_cvt<<<dim3(3072 / 32, 32), 256, 0, stream>>>(w_attn, wat, 3072);
  transpose_cvt<<<dim3(1024 / 32, 32), 256, 0, stream>>>(w_proj, wpt, 1024);

  gemm_bf16<0><<<dim3(3072 / 128, 8192 / 128), 256, 0, stream>>>(
      xb, wat, b_attn, nullptr, qb, kb, vt);

  attn_kernel<<<dim3(16, 4 * HB), 256, 0, stream>>>(qb, kb, vt, yb);

  gemm_bf16<1><<<dim3(1024 / 128, 8192 / 128), 256, 0, stream>>>(
      yb, wpt, b_proj, out, nullptr, nullptr, nullptr);
}

// Round 7
// 186.774 us; speedup vs baseline: 1.1451x; 1.1451x over previous
//
#include <hip/hip_runtime.h>
#include <hip/hip_bf16.h>

typedef __bf16 bf16x8 __attribute__((ext_vector_type(8)));
typedef float f32x4 __attribute__((ext_vector_type(4)));
typedef unsigned short u16x8 __attribute__((ext_vector_type(8)));
typedef unsigned short u16x4 __attribute__((ext_vector_type(4)));

#define HB 16
#define TT 2048
#define CCH 1024
#define DD 64

#define AS1 __attribute__((address_space(1)))
#define AS3 __attribute__((address_space(3)))
#define GL16(gp, lp) __builtin_amdgcn_global_load_lds((const AS1 void*)(gp), (AS3 void*)(lp), 16, 0, 0)

__device__ __forceinline__ unsigned short f2bf(float f) {
  union { __hip_bfloat16 h; unsigned short u; } cv;
  cv.h = __float2bfloat16(f);
  return cv.u;
}

__device__ __forceinline__ f32x4 mfma16(bf16x8 a, bf16x8 b, f32x4 c) {
  return __builtin_amdgcn_mfma_f32_16x16x32_bf16(a, b, c, 0, 0, 0);
}

// ---------------- conversion kernels ----------------

__global__ __launch_bounds__(256) void cvt_f32_bf16(const float* __restrict__ in,
                                                    unsigned short* __restrict__ out,
                                                    int n4) {
  int i = blockIdx.x * 256 + threadIdx.x;
  if (i >= n4) return;
  float4 v = reinterpret_cast<const float4*>(in)[i];
  u16x4 o;
  o.x = f2bf(v.x); o.y = f2bf(v.y); o.z = f2bf(v.z); o.w = f2bf(v.w);
  *reinterpret_cast<u16x4*>(out + (size_t)i * 4) = o;
}

// w: [1024 x N] fp32  ->  wt: [N x 1024] bf16 (transposed)
__global__ __launch_bounds__(256) void transpose_cvt(const float* __restrict__ w,
                                                     unsigned short* __restrict__ wt,
                                                     int N) {
  __shared__ unsigned short t[32][33];
  int nb = blockIdx.x * 32, kb = blockIdx.y * 32;
  int tx = threadIdx.x & 31, ty = threadIdx.x >> 5;  // ty 0..7
  #pragma unroll
  for (int r = 0; r < 32; r += 8)
    t[ty + r][tx] = f2bf(w[(size_t)(kb + ty + r) * N + nb + tx]);
  __syncthreads();
  #pragma unroll
  for (int r = 0; r < 32; r += 8)
    wt[(size_t)(nb + ty + r) * 1024 + kb + tx] = t[tx][ty + r];
}

// ---------------- GEMM (m97 structure): C = A @ Bt^T (+bias) ----------------
// 1-D grid + XCD-bijective swizzle: work = (bid&7)*(nwg/8) + bid>>3,
// m0 = work / nbx (row-major work order -> consecutive work shares A-panel).

template <int EPI>
__global__ __launch_bounds__(256) void gemm_bf16(
    const unsigned short* __restrict__ A,
    const unsigned short* __restrict__ Bt,
    const float* __restrict__ bias,
    float* __restrict__ outf,
    unsigned short* __restrict__ qb,
    unsigned short* __restrict__ kb,
    unsigned short* __restrict__ vt,
    int nbx, int wpx) {  // nbx = n-blocks, wpx = nwg/8
  __shared__ unsigned short As[8192];  // [128][64] linear
  __shared__ unsigned short Bs[8192];
  const int bid = blockIdx.x;
  const int work = (bid & 7) * wpx + (bid >> 3);
  const int m0 = (work / nbx) * 128, n0 = (work % nbx) * 128;
  const int tid = threadIdx.x;
  const int lane = tid & 63;
  const int wid = tid >> 6;
  const int r16 = lane & 15, g = lane >> 4;
  const int wm = wid >> 1, wn = wid & 1;
  const int srow = tid >> 3;                 // 0..31 (+32 per instr)
  const int schx = (tid & 7) ^ (srow & 7);   // XOR-swizzled source chunk

  f32x4 acc[4][4];
  #pragma unroll
  for (int i = 0; i < 4; ++i)
    #pragma unroll
    for (int j = 0; j < 4; ++j) acc[i][j] = (f32x4){0.f, 0.f, 0.f, 0.f};

  const int rx = r16 & 7;

  for (int kt = 0; kt < 1024; kt += 64) {
    #pragma unroll
    for (int i = 0; i < 4; ++i) {
      const int row = i * 32 + srow;
      GL16(A + (size_t)(m0 + row) * 1024 + kt + schx * 8, As + i * 2048 + tid * 8);
    }
    #pragma unroll
    for (int i = 0; i < 4; ++i) {
      const int row = i * 32 + srow;
      GL16(Bt + (size_t)(n0 + row) * 1024 + kt + schx * 8, Bs + i * 2048 + tid * 8);
    }
    __syncthreads();
    #pragma unroll
    for (int h = 0; h < 2; ++h) {
      bf16x8 af[4], bfr[4];
      #pragma unroll
      for (int i = 0; i < 4; ++i)
        af[i] = *reinterpret_cast<const bf16x8*>(
            &As[(wm * 64 + i * 16 + r16) * 64 + ((g + 4 * h) ^ rx) * 8]);
      #pragma unroll
      for (int j = 0; j < 4; ++j)
        bfr[j] = *reinterpret_cast<const bf16x8*>(
            &Bs[(wn * 64 + j * 16 + r16) * 64 + ((g + 4 * h) ^ rx) * 8]);
      #pragma unroll
      for (int i = 0; i < 4; ++i)
        #pragma unroll
        for (int j = 0; j < 4; ++j)
          acc[i][j] = mfma16(af[i], bfr[j], acc[i][j]);
    }
    __syncthreads();
  }

  #pragma unroll
  for (int i = 0; i < 4; ++i) {
    #pragma unroll
    for (int j = 0; j < 4; ++j) {
      const int n = n0 + wn * 64 + j * 16 + r16;
      const int mbase = m0 + wm * 64 + i * 16 + g * 4;
      const float bi = bias[n];
      if (EPI == 1) {
        #pragma unroll
        for (int r = 0; r < 4; ++r)
          outf[(size_t)(mbase + r) * 1024 + n] = acc[i][j][r] + bi;
      } else {
        const int which = n >> 10;
        const int cc2 = n & 1023;
        const int h = cc2 >> 6, d = cc2 & 63;
        const int b = mbase >> 11, t = mbase & 2047;
        if (which == 2) {
          u16x4 o;
          #pragma unroll
          for (int r = 0; r < 4; ++r) o[r] = f2bf(acc[i][j][r] + bi);
          *reinterpret_cast<u16x4*>(
              &vt[(((size_t)b * HB + h) * DD + d) * TT + t]) = o;
        } else {
          unsigned short* dst = (which == 0) ? qb : kb;
          // q folded scale: 1/sqrt(64) * log2(e)  (exp2-domain softmax)
          const float sc = (which == 0) ? 0.18033688011112042f : 1.0f;
          #pragma unroll
          for (int r = 0; r < 4; ++r)
            dst[(((size_t)b * HB + h) * TT + (t + r)) * DD + d] =
                f2bf((acc[i][j][r] + bi) * sc);
        }
      }
    }
  }
}

// ---------------- flash attention (round-4 structure + XCD swizzle) ----------
// 1-D grid 512 blocks, 512 thr = 8 waves, KVBLK=128, 16 q-rows/wave.
// XCD swizzle: work = (bid&7)*64 + bid>>3; bh = work>>3; jb = work&7
//   -> each head's 8 blocks land on ONE XCD (4 MB K/V set fits its L2),
//      all 512 blocks co-resident (2/CU), zero dispatch tail.
// Triangle pairing: part0 = q-group jb, part1 = q-group 15-jb -> 17 tiles/blk.

__global__ __launch_bounds__(512, 2) void attn_kernel(
    const unsigned short* __restrict__ qg_,
    const unsigned short* __restrict__ kg_,
    const unsigned short* __restrict__ vtg_,
    unsigned short* __restrict__ yb) {
  const int bid = blockIdx.x;
  const int work = (bid & 7) * 64 + (bid >> 3);
  const int bh = work >> 3;
  const int jb = work & 7;
  const int tid = threadIdx.x;
  const int wid = tid >> 6;
  const int lane = tid & 63;
  const int r16 = lane & 15, g = lane >> 4;
  const unsigned short* Q = qg_ + (size_t)bh * TT * DD;
  const unsigned short* K = kg_ + (size_t)bh * TT * DD;
  const unsigned short* Vt = vtg_ + (size_t)bh * DD * TT;
  const int b = bh >> 4, h = bh & 15;

  // buf: [K 8192 elems = [128][64]] [V 8192 elems = [64][128]]
  __shared__ unsigned short smem[2][16384];

  const int krow0 = tid >> 3;                    // 0..63 (+64 per instr)
  const int kchx = (tid & 7) ^ (krow0 & 7);      // K source chunk (XOR swz)
  const int vd0 = tid >> 4;                      // 0..31 (+32 per instr)
  const int vchx = (tid & 15) ^ (vd0 & 7);       // V source chunk (XOR swz)
  const int rx = r16 & 7;

#define STAGE(bi, kvb_) do {                                                      \
    unsigned short* sb_ = &smem[bi][0];                                           \
    const unsigned short* gk_ = K + (size_t)(kvb_) * DD;                          \
    GL16(gk_ + (size_t)krow0 * DD + kchx * 8,              sb_ + tid * 8);        \
    GL16(gk_ + (size_t)(64 + krow0) * DD + kchx * 8,       sb_ + 4096 + tid * 8); \
    GL16(Vt + (size_t)vd0 * TT + (kvb_) + vchx * 8,        sb_ + 8192 + tid * 8); \
    GL16(Vt + (size_t)(32 + vd0) * TT + (kvb_) + vchx * 8, sb_ + 12288 + tid * 8);\
  } while (0)

  #pragma unroll
  for (int part = 0; part < 2; ++part) {
    const int qg0 = (part == 0) ? jb * 128 : (15 - jb) * 128;
    const int nt = (part == 0) ? (jb + 1) : (16 - jb);
    const int qw = qg0 + wid * 16;
    const int q = qw + r16;  // this lane's q row

    bf16x8 qf0 = *reinterpret_cast<const bf16x8*>(&Q[(size_t)q * DD + g * 8]);
    bf16x8 qf1 = *reinterpret_cast<const bf16x8*>(&Q[(size_t)q * DD + 32 + g * 8]);

    f32x4 yacc[4];
    #pragma unroll
    for (int db = 0; db < 4; ++db) yacc[db] = (f32x4){0.f, 0.f, 0.f, 0.f};
    float m = -1e30f, l = 0.f;

    STAGE(0, 0);  // tile 0
    if (nt > 1) {
      STAGE(1, 128);
      asm volatile("s_waitcnt vmcnt(4)" ::: "memory");
    } else {
      asm volatile("s_waitcnt vmcnt(0)" ::: "memory");
    }
    __builtin_amdgcn_s_barrier();

    for (int t = 0; t < nt; ++t) {
      const int kvb = t * 128;
      const unsigned short* sK = &smem[t & 1][0];
      const unsigned short* sV = &smem[t & 1][8192];

      // ---- S^T = K Q^T : lane holds S^T[kvb + c*16 + 4g + r][q] ----
      float s[8][4];
      #pragma unroll
      for (int c = 0; c < 8; ++c) {
        bf16x8 kfa = *reinterpret_cast<const bf16x8*>(
            &sK[(c * 16 + r16) * 64 + (g ^ rx) * 8]);
        bf16x8 kfb = *reinterpret_cast<const bf16x8*>(
            &sK[(c * 16 + r16) * 64 + ((g + 4) ^ rx) * 8]);
        f32x4 z = (f32x4){0.f, 0.f, 0.f, 0.f};
        z = mfma16(kfa, qf0, z);
        z = mfma16(kfb, qf1, z);
        #pragma unroll
        for (int r = 0; r < 4; ++r) s[c][r] = z[r];
      }

      // ---- mask (last tile only) + max ----
      float mx = -1e30f;
      if (t == nt - 1) {
        #pragma unroll
        for (int c = 0; c < 8; ++c)
          #pragma unroll
          for (int r = 0; r < 4; ++r) {
            if (kvb + c * 16 + 4 * g + r > q) s[c][r] = -1e30f;
            mx = fmaxf(mx, s[c][r]);
          }
      } else {
        #pragma unroll
        for (int c = 0; c < 8; ++c)
          #pragma unroll
          for (int r = 0; r < 4; ++r) mx = fmaxf(mx, s[c][r]);
      }
      mx = fmaxf(mx, __shfl_xor(mx, 16));
      mx = fmaxf(mx, __shfl_xor(mx, 32));

      // ---- defer-max (T13, exp2 domain, THR=8) ----
      if (!__all(mx <= m + 8.f)) {
        const float mn = fmaxf(m, mx);
        const float al = exp2f(m - mn);
        m = mn;
        l *= al;
        #pragma unroll
        for (int db = 0; db < 4; ++db)
          #pragma unroll
          for (int r = 0; r < 4; ++r) yacc[db][r] *= al;
      }
      float rs = 0.f;
      #pragma unroll
      for (int c = 0; c < 8; ++c)
        #pragma unroll
        for (int r = 0; r < 4; ++r) {
          s[c][r] = exp2f(s[c][r] - m);
          rs += s[c][r];
        }
      rs += __shfl_xor(rs, 16);
      rs += __shfl_xor(rs, 32);
      l += rs;

      // ---- PV: per kk, build P^T B-frag by shuffles, A = V from LDS ----
      const int s0l = r16 + 16 * ((2 * g) & 3);
      const int s1l = r16 + 16 * ((2 * g + 1) & 3);
      #pragma unroll
      for (int kk = 0; kk < 4; ++kk) {
        unsigned x0, x1, y0, y1;
        asm("v_cvt_pk_bf16_f32 %0, %1, %2" : "=v"(x0) : "v"(s[2*kk][0]), "v"(s[2*kk][1]));
        asm("v_cvt_pk_bf16_f32 %0, %1, %2" : "=v"(x1) : "v"(s[2*kk][2]), "v"(s[2*kk][3]));
        asm("v_cvt_pk_bf16_f32 %0, %1, %2" : "=v"(y0) : "v"(s[2*kk+1][0]), "v"(s[2*kk+1][1]));
        asm("v_cvt_pk_bf16_f32 %0, %1, %2" : "=v"(y1) : "v"(s[2*kk+1][2]), "v"(s[2*kk+1][3]));
        unsigned a0 = __shfl((int)x0, s0l, 64);
        unsigned b0 = __shfl((int)y0, s0l, 64);
        unsigned a1 = __shfl((int)x1, s0l, 64);
        unsigned b1 = __shfl((int)y1, s0l, 64);
        unsigned a2 = __shfl((int)x0, s1l, 64);
        unsigned b2 = __shfl((int)y0, s1l, 64);
        unsigned a3 = __shfl((int)x1, s1l, 64);
        unsigned b3 = __shfl((int)y1, s1l, 64);
        union { unsigned w[4]; bf16x8 v; } pf;
        pf.w[0] = (g < 2) ? a0 : b0;
        pf.w[1] = (g < 2) ? a1 : b1;
        pf.w[2] = (g < 2) ? a2 : b2;
        pf.w[3] = (g < 2) ? a3 : b3;
        #pragma unroll
        for (int db = 0; db < 4; ++db) {
          bf16x8 vf = *reinterpret_cast<const bf16x8*>(
              &sV[(db * 16 + r16) * 128 + ((kk * 4 + g) ^ rx) * 8]);
          yacc[db] = mfma16(vf, pf.v, yacc[db]);
        }
      }

      __syncthreads();  // all waves done with buf[t&1]; drains in-flight t+1
      if (t + 2 < nt) STAGE(t & 1, (t + 2) * 128);
    }

    // ---- epilogue: y = yacc / l ----
    const float rl = 1.0f / l;
    #pragma unroll
    for (int db = 0; db < 4; ++db) {
      u16x4 o;
      #pragma unroll
      for (int r = 0; r < 4; ++r) o[r] = f2bf(yacc[db][r] * rl);
      *reinterpret_cast<u16x4*>(
          &yb[((size_t)b * TT + q) * CCH + h * DD + db * 16 + 4 * g]) = o;
    }
  }
#undef STAGE
}

// ---------------- launcher ----------------

extern "C" void kernel_launch(void* const* d_in, const int* in_sizes, int n_in,
                              void* d_out, int out_size, void* d_ws, size_t ws_size,
                              hipStream_t stream) {
  const float* x      = (const float*)d_in[0];
  const float* w_attn = (const float*)d_in[1];
  const float* b_attn = (const float*)d_in[2];
  const float* w_proj = (const float*)d_in[3];
  const float* b_proj = (const float*)d_in[4];
  float* out = (float*)d_out;
  char* ws = (char*)d_ws;

  unsigned short* xb  = (unsigned short*)(ws + 0);          // 16 MB
  unsigned short* wat = (unsigned short*)(ws + 16777216);   // 6 MB  [3072][1024]
  unsigned short* wpt = (unsigned short*)(ws + 23068672);   // 2 MB  [1024][1024]
  unsigned short* qb  = (unsigned short*)(ws + 25165824);   // 16 MB [B,H,T,D]
  unsigned short* kb  = (unsigned short*)(ws + 41943040);   // 16 MB [B,H,T,D]
  unsigned short* vt  = (unsigned short*)(ws + 58720256);   // 16 MB [B,H,D,T]
  unsigned short* yb  = (unsigned short*)(ws + 75497472);   // 16 MB [B,T,C]

  cvt_f32_bf16<<<(8192 * 1024 / 4 + 255) / 256, 256, 0, stream>>>(x, xb, 8192 * 1024 / 4);
  transpose_cvt<<<dim3(3072 / 32, 32), 256, 0, stream>>>(w_attn, wat, 3072);
  transpose_cvt<<<dim3(1024 / 32, 32), 256, 0, stream>>>(w_proj, wpt, 1024);

  // QKV GEMM: 64 m-blocks x 24 n-blocks = 1536 wg; wpx = 192
  gemm_bf16<0><<<1536, 256, 0, stream>>>(
      xb, wat, b_attn, nullptr, qb, kb, vt, 24, 192);

  attn_kernel<<<512, 512, 0, stream>>>(qb, kb, vt, yb);

  // proj GEMM: 64 m-blocks x 8 n-blocks = 512 wg; wpx = 64
  gemm_bf16<1><<<512, 256, 0, stream>>>(
      yb, wpt, b_proj, out, nullptr, nullptr, nullptr, 8, 64);
}